// Round 7
// baseline (1784.839 us; speedup 1.0000x reference)
//
#include <hip/hip_runtime.h>
#include <hip/hip_bf16.h>
#include <math.h>

#define N_EDGESC  1048576
#define N_GRAPHSC 8192
#define NPG 32     // nodes per graph
#define EPG 128    // edges per graph
#define FXD 78
#define F2C 156
#define F3C 312
#define GHC 156    // Wg1 out
#define GOC 128    // Wg2 out
#define HS  36     // padded node-stride (fp32 k-major tiles)
#define HBS 168    // Hb row stride in shorts
#define RBK 16     // rows per block in MLP kernels

typedef __attribute__((ext_vector_type(8))) short short8v;   // 8 bf16 = 4 VGPR
typedef __attribute__((ext_vector_type(4))) float float4v;

__device__ __forceinline__ short f2bf(float x) {  // RNE truncate f32->bf16 bits
  unsigned u = __float_as_uint(x);
  u += 0x7FFFu + ((u >> 16) & 1u);
  return (short)(u >> 16);
}

// ---------------------------------------------------------------------------
// A-aggregation: reads fp32 k-major H, emits bf16 node-major Hb[r][k].
template<int FIN, int ROWS>
__device__ __forceinline__ void a_mult_bf(const float* __restrict__ H,
                                          const float* __restrict__ As,
                                          short* __restrict__ Hb, int t) {
  const int r0 = (t & 7) * 4;
  const int g = t >> 3;
  float acc[ROWS][4];
#pragma unroll
  for (int j = 0; j < ROWS; ++j)
    acc[j][0] = acc[j][1] = acc[j][2] = acc[j][3] = 0.f;
#pragma unroll
  for (int c = 0; c < NPG; c += 4) {
    float4 a0 = *(const float4*)(As + (c + 0) * HS + r0);
    float4 a1 = *(const float4*)(As + (c + 1) * HS + r0);
    float4 a2 = *(const float4*)(As + (c + 2) * HS + r0);
    float4 a3 = *(const float4*)(As + (c + 3) * HS + r0);
#pragma unroll
    for (int j = 0; j < ROWS; ++j) {
      int k = g + 32 * j;
      if (k < FIN) {
        float4 h4 = *(const float4*)(H + k * HS + c);
        acc[j][0] = fmaf(h4.x, a0.x, acc[j][0]); acc[j][1] = fmaf(h4.x, a0.y, acc[j][1]);
        acc[j][2] = fmaf(h4.x, a0.z, acc[j][2]); acc[j][3] = fmaf(h4.x, a0.w, acc[j][3]);
        acc[j][0] = fmaf(h4.y, a1.x, acc[j][0]); acc[j][1] = fmaf(h4.y, a1.y, acc[j][1]);
        acc[j][2] = fmaf(h4.y, a1.z, acc[j][2]); acc[j][3] = fmaf(h4.y, a1.w, acc[j][3]);
        acc[j][0] = fmaf(h4.z, a2.x, acc[j][0]); acc[j][1] = fmaf(h4.z, a2.y, acc[j][1]);
        acc[j][2] = fmaf(h4.z, a2.z, acc[j][2]); acc[j][3] = fmaf(h4.z, a2.w, acc[j][3]);
        acc[j][0] = fmaf(h4.w, a3.x, acc[j][0]); acc[j][1] = fmaf(h4.w, a3.y, acc[j][1]);
        acc[j][2] = fmaf(h4.w, a3.z, acc[j][2]); acc[j][3] = fmaf(h4.w, a3.w, acc[j][3]);
      }
    }
  }
#pragma unroll
  for (int j = 0; j < ROWS; ++j) {
    int k = g + 32 * j;
    if (k < FIN) {
#pragma unroll
      for (int i = 0; i < 4; ++i)
        Hb[(r0 + i) * HBS + k] = f2bf(acc[j][i]);
    }
  }
}

// ---------------------------------------------------------------------------
// MFMA mm: D[m][f] = sum_k Hb[m][k] * Wt[f][k] (+bias, relu / pool).
template<int KSTEPS, int NT, int KP, int FOUT, bool POOL>
__device__ __forceinline__ void mm_mfma(const short* __restrict__ Hb,
                                        const short* __restrict__ Wt,
                                        const float* __restrict__ bias,
                                        float* __restrict__ Hout,
                                        unsigned* __restrict__ gmax, int t) {
  const int w = t >> 6;
  const int L = t & 63;
  const int q = L >> 4;
  const int mt = w & 1;                 // wave -> fixed m-tile (A-frag reuse)
  const int m = mt * 16 + (L & 15);
  short8v afrag[KSTEPS];
#pragma unroll
  for (int s = 0; s < KSTEPS; ++s)
    afrag[s] = *(const short8v*)(Hb + m * HBS + s * 32 + q * 8);
  for (int nt = (w >> 1); nt < NT; nt += 2) {
    const int f = nt * 16 + (L & 15);
    float4v acc = {0.f, 0.f, 0.f, 0.f};
#pragma unroll
    for (int s = 0; s < KSTEPS; ++s) {
      short8v bfrag = *(const short8v*)(Wt + (size_t)f * KP + s * 32 + q * 8);
      acc = __builtin_amdgcn_mfma_f32_16x16x32_bf16(afrag[s], bfrag, acc, 0, 0, 0);
    }
    if (f < FOUT) {
      float bb = bias[f];
      float o0 = fmaxf(acc[0] + bb, 0.f), o1 = fmaxf(acc[1] + bb, 0.f);
      float o2 = fmaxf(acc[2] + bb, 0.f), o3 = fmaxf(acc[3] + bb, 0.f);
      if constexpr (POOL) {
        float mx = fmaxf(fmaxf(o0, o1), fmaxf(o2, o3));
        atomicMax(&gmax[f], __float_as_uint(mx));   // relu'd >= 0 -> monotone
      } else {
        float4 o = {o0, o1, o2, o3};
        *(float4*)(Hout + f * HS + mt * 16 + q * 4) = o;
      }
    }
  }
}

// ---------------------------------------------------------------------------
// Weight pre-pack: Wt[f][k] = bf16(W[k][f]), zero-padded to Np x Kp.
__global__ __launch_bounds__(256)
void pack_wt(const float* __restrict__ src, short* __restrict__ dst,
             int FIN, int FOUT, int Kp, int Np) {
  int idx = blockIdx.x * 256 + threadIdx.x;
  if (idx >= Np * Kp) return;
  int f = idx / Kp, k = idx - f * Kp;
  float v = (f < FOUT && k < FIN) ? src[(size_t)k * FOUT + f] : 0.f;
  dst[idx] = f2bf(v);
}

// ---------------------------------------------------------------------------
// One block per graph, blockIdx.y = drug. LDS 37824 B -> 4 blocks/CU.
// Aliasing: Y == X rows 78..155 (disjoint lifetime); gbuf == As (dead after
// last a_mult); deg == Y region (dead after As built).
__global__ __launch_bounds__(256, 4)
void drug_kernel(const float* __restrict__ x1, const int* __restrict__ ei1,
                 const float* __restrict__ x2, const int* __restrict__ ei2,
                 const short* __restrict__ Wt1, const float* __restrict__ b1,
                 const short* __restrict__ Wt2, const float* __restrict__ b2,
                 const short* __restrict__ Wt3, const float* __restrict__ b3,
                 float* __restrict__ gpool) {
  __shared__ __align__(16) float X[F2C * HS];    // 22464 B
  __shared__ __align__(16) float As[NPG * HS];   //  4608 B
  __shared__ __align__(16) short Hb[NPG * HBS];  // 10752 B
  float* Y = X + FXD * HS;        // rows 78..155 of X
  float* deg = Y;                 // [0..31]; dead before L1-mm writes Y
  float* gbuf = As;               // alias after final a_mult (As dead)
  unsigned* gbufU = (unsigned*)As;

  const int t = threadIdx.x;
  const int gid = blockIdx.x;
  const int drug = blockIdx.y;
  const float* __restrict__ x = drug ? x2 : x1;
  const int* __restrict__ ei = drug ? ei2 : ei1;
  const int nbase = gid * NPG;

  // ---- P0: zero deg/As/Hb, load x^T -> X rows 0..77
  if (t < NPG) deg[t] = 0.f;
  for (int i = t; i < NPG * HS; i += 256) As[i] = 0.f;
  for (int i = t; i < NPG * HBS / 2; i += 256) ((int*)Hb)[i] = 0;
  const float* xg = x + (size_t)gid * (NPG * FXD);
  for (int i = t; i < (NPG * FXD) / 4; i += 256) {
    float4 v = ((const float4*)xg)[i];
    const float* vp = (const float*)&v;
    int idx = i * 4;
#pragma unroll
    for (int j = 0; j < 4; ++j) {
      int id2 = idx + j;
      int n = id2 / FXD;
      int k = id2 - n * FXD;
      X[k * HS + n] = vp[j];
    }
  }
  int s = 0, d = 0;
  if (t < EPG) {
    s = ei[(size_t)gid * EPG + t] - nbase;
    d = ei[(size_t)N_EDGESC + (size_t)gid * EPG + t] - nbase;
  }
  __syncthreads();
  if (t < EPG) atomicAdd(&deg[s], 1.0f);
  __syncthreads();
  if (t < EPG) {
    float w = rsqrtf(deg[s] + 1.0f) * rsqrtf(deg[d] + 1.0f);
    atomicAdd(&As[d * HS + s], w);   // A[s][d]: msg d->s
  }
  if (t < NPG) atomicAdd(&As[t * HS + t], 1.0f / (deg[t] + 1.0f));
  __syncthreads();

  // ---- layer 1: A*x -> Hb ; MFMA -> Y (X rows 78..155)
  a_mult_bf<FXD, 3>(X, As, Hb, t);
  __syncthreads();                      // deg dead; Y free to write
  mm_mfma<3, 5, 96, FXD, false>(Hb, Wt1, b1, Y, nullptr, t);
  __syncthreads();
  // ---- layer 2: A*h1 -> Hb ; MFMA -> X full (rows 0..155, overwrites Y)
  a_mult_bf<FXD, 3>(Y, As, Hb, t);
  __syncthreads();
  mm_mfma<3, 10, 96, F2C, false>(Hb, Wt2, b2, X, nullptr, t);
  __syncthreads();
  // ---- layer 3 + pool: A*h2 -> Hb ; zero gbuf (As dead) ; MFMA+pool
  a_mult_bf<F2C, 5>(X, As, Hb, t);
  __syncthreads();
  for (int i = t; i < F3C; i += 256) gbufU[i] = 0u;
  __syncthreads();
  mm_mfma<5, 20, 160, F3C, true>(Hb, Wt3, b3, nullptr, gbufU, t);
  __syncthreads();
  // ---- emit pooled vector (graph-MLP moved to gmlp_kernel)
  for (int i = t; i < F3C; i += 256)
    gpool[((size_t)drug * N_GRAPHSC + gid) * F3C + i] = __uint_as_float(gbufU[i]);
}

// ---------------------------------------------------------------------------
// Batched graph-MLP: gout[r] = relu(gpool[r] @ Wg1 + bg1) @ Wg2 + bg2
// 16 rows/block over 16384 rows; cell-style transposed LDS tiles.
__global__ __launch_bounds__(256, 4)
void gmlp_kernel(const float* __restrict__ gpool,
                 const float* __restrict__ Wg1, const float* __restrict__ bg1,
                 const float* __restrict__ Wg2, const float* __restrict__ bg2,
                 float* __restrict__ gout) {
  __shared__ __align__(16) float U[F3C * RBK];   // 19968 B; h1 aliases after
  const int t = threadIdx.x;
  const int R = blockIdx.x * RBK;
  const int r0 = (t & 3) * 4;
  const int f = t >> 2;  // [0,64)

  for (int i = t; i < RBK * (F3C / 4); i += 256) {   // 16 rows x 78 float4
    int r = i / 78, k4 = i - r * 78;
    float4 v = *(const float4*)(gpool + (size_t)(R + r) * F3C + k4 * 4);
    int kk = k4 * 4;
    U[(kk + 0) * RBK + r] = v.x; U[(kk + 1) * RBK + r] = v.y;
    U[(kk + 2) * RBK + r] = v.z; U[(kk + 3) * RBK + r] = v.w;
  }
  __syncthreads();

  float acc[4][3];
#pragma unroll
  for (int i = 0; i < 4; ++i)
#pragma unroll
    for (int j = 0; j < 3; ++j) acc[i][j] = 0.f;
  const bool f3 = (f < GHC - 128);   // third feature slot valid (f<28)
#pragma unroll 4
  for (int k = 0; k < F3C; ++k) {
    float4 h = *(const float4*)(U + k * RBK + r0);
    const float* wr = Wg1 + (size_t)k * GHC + f;
    float w0 = wr[0], w1 = wr[64];
    float w2 = f3 ? wr[128] : 0.f;
    acc[0][0] = fmaf(h.x, w0, acc[0][0]); acc[1][0] = fmaf(h.y, w0, acc[1][0]);
    acc[2][0] = fmaf(h.z, w0, acc[2][0]); acc[3][0] = fmaf(h.w, w0, acc[3][0]);
    acc[0][1] = fmaf(h.x, w1, acc[0][1]); acc[1][1] = fmaf(h.y, w1, acc[1][1]);
    acc[2][1] = fmaf(h.z, w1, acc[2][1]); acc[3][1] = fmaf(h.w, w1, acc[3][1]);
    acc[0][2] = fmaf(h.x, w2, acc[0][2]); acc[1][2] = fmaf(h.y, w2, acc[1][2]);
    acc[2][2] = fmaf(h.z, w2, acc[2][2]); acc[3][2] = fmaf(h.w, w2, acc[3][2]);
  }
  __syncthreads();   // all U reads done -> reuse as h1[156 x 16]
#pragma unroll
  for (int j = 0; j < 3; ++j) {
    int ff = f + j * 64;
    if (ff < GHC) {
      float bb = bg1[ff];
      float4 o;
      o.x = fmaxf(acc[0][j] + bb, 0.f); o.y = fmaxf(acc[1][j] + bb, 0.f);
      o.z = fmaxf(acc[2][j] + bb, 0.f); o.w = fmaxf(acc[3][j] + bb, 0.f);
      *(float4*)(U + ff * RBK + r0) = o;
    }
  }
  __syncthreads();

  float a2[4][2];
#pragma unroll
  for (int i = 0; i < 4; ++i) { a2[i][0] = 0.f; a2[i][1] = 0.f; }
#pragma unroll 4
  for (int k = 0; k < GHC; ++k) {
    float4 h = *(const float4*)(U + k * RBK + r0);
    const float* wr = Wg2 + (size_t)k * GOC + f;
    float w0 = wr[0], w1 = wr[64];
    a2[0][0] = fmaf(h.x, w0, a2[0][0]); a2[1][0] = fmaf(h.y, w0, a2[1][0]);
    a2[2][0] = fmaf(h.z, w0, a2[2][0]); a2[3][0] = fmaf(h.w, w0, a2[3][0]);
    a2[0][1] = fmaf(h.x, w1, a2[0][1]); a2[1][1] = fmaf(h.y, w1, a2[1][1]);
    a2[2][1] = fmaf(h.z, w1, a2[2][1]); a2[3][1] = fmaf(h.w, w1, a2[3][1]);
  }
#pragma unroll
  for (int j = 0; j < 2; ++j) {
    int ff = f + j * 64;
    float bb = bg2[ff];
#pragma unroll
    for (int i = 0; i < 4; ++i)
      gout[(size_t)(R + r0 + i) * GOC + ff] = a2[i][j] + bb;
  }
}

// ---------------------------------------------------------------------------
// Cell MLP (R3-proven): 16 rows/block, 4x8 microtile.
__global__ __launch_bounds__(256, 3)
void cell_kernel(const float* __restrict__ cell,
                 const float* __restrict__ Wr1, const float* __restrict__ br1,
                 const float* __restrict__ Wr2, const float* __restrict__ br2,
                 const float* __restrict__ Wr3, const float* __restrict__ br3,
                 float* __restrict__ cout) {
  __shared__ __align__(16) float U[512 * RBK];
  __shared__ __align__(16) float h2[256 * RBK];
  const int t = threadIdx.x;
  const int R = blockIdx.x * RBK;
  const int r0 = (t & 3) * 4;
  const int f = t >> 2;

  float acc[4][8];
#pragma unroll
  for (int i = 0; i < 4; ++i)
#pragma unroll
    for (int j = 0; j < 8; ++j) acc[i][j] = 0.f;

  for (int k0 = 0; k0 < 1000; k0 += 200) {
    __syncthreads();
    for (int i = t; i < 800; i += 256) {
      int r = i / 50, k4 = i - r * 50;
      float4 v = *(const float4*)(cell + (size_t)(R + r) * 1000 + k0 + k4 * 4);
      int kk = k4 * 4;
      U[(kk + 0) * RBK + r] = v.x; U[(kk + 1) * RBK + r] = v.y;
      U[(kk + 2) * RBK + r] = v.z; U[(kk + 3) * RBK + r] = v.w;
    }
    __syncthreads();
#pragma unroll 4
    for (int k = 0; k < 200; ++k) {
      float4 h = *(const float4*)(U + k * RBK + r0);
      const float* wr = Wr1 + (size_t)(k0 + k) * 512 + f;
#pragma unroll
      for (int j = 0; j < 8; ++j) {
        float w = wr[j * 64];
        acc[0][j] = fmaf(h.x, w, acc[0][j]);
        acc[1][j] = fmaf(h.y, w, acc[1][j]);
        acc[2][j] = fmaf(h.z, w, acc[2][j]);
        acc[3][j] = fmaf(h.w, w, acc[3][j]);
      }
    }
  }
  __syncthreads();
#pragma unroll
  for (int j = 0; j < 8; ++j) {
    int ff = f + j * 64;
    float bb = br1[ff];
    float4 o;
    o.x = fmaxf(acc[0][j] + bb, 0.f); o.y = fmaxf(acc[1][j] + bb, 0.f);
    o.z = fmaxf(acc[2][j] + bb, 0.f); o.w = fmaxf(acc[3][j] + bb, 0.f);
    *(float4*)(U + ff * RBK + r0) = o;
  }
  __syncthreads();

  float a2[4][4];
#pragma unroll
  for (int i = 0; i < 4; ++i)
#pragma unroll
    for (int j = 0; j < 4; ++j) a2[i][j] = 0.f;
#pragma unroll 4
  for (int k = 0; k < 512; ++k) {
    float4 h = *(const float4*)(U + k * RBK + r0);
    const float* wr = Wr2 + (size_t)k * 256 + f;
#pragma unroll
    for (int j = 0; j < 4; ++j) {
      float w = wr[j * 64];
      a2[0][j] = fmaf(h.x, w, a2[0][j]);
      a2[1][j] = fmaf(h.y, w, a2[1][j]);
      a2[2][j] = fmaf(h.z, w, a2[2][j]);
      a2[3][j] = fmaf(h.w, w, a2[3][j]);
    }
  }
#pragma unroll
  for (int j = 0; j < 4; ++j) {
    int ff = f + j * 64;
    float bb = br2[ff];
    float4 o;
    o.x = fmaxf(a2[0][j] + bb, 0.f); o.y = fmaxf(a2[1][j] + bb, 0.f);
    o.z = fmaxf(a2[2][j] + bb, 0.f); o.w = fmaxf(a2[3][j] + bb, 0.f);
    *(float4*)(h2 + ff * RBK + r0) = o;
  }
  __syncthreads();

  float a3[4][2];
#pragma unroll
  for (int i = 0; i < 4; ++i) { a3[i][0] = 0.f; a3[i][1] = 0.f; }
#pragma unroll 4
  for (int k = 0; k < 256; ++k) {
    float4 h = *(const float4*)(h2 + k * RBK + r0);
    const float* wr = Wr3 + (size_t)k * 128 + f;
#pragma unroll
    for (int j = 0; j < 2; ++j) {
      float w = wr[j * 64];
      a3[0][j] = fmaf(h.x, w, a3[0][j]);
      a3[1][j] = fmaf(h.y, w, a3[1][j]);
      a3[2][j] = fmaf(h.z, w, a3[2][j]);
      a3[3][j] = fmaf(h.w, w, a3[3][j]);
    }
  }
#pragma unroll
  for (int j = 0; j < 2; ++j) {
    int ff = f + j * 64;
    float bb = br3[ff];
#pragma unroll
    for (int i = 0; i < 4; ++i)
      cout[(size_t)(R + r0 + i) * GOC + ff] = a3[i][j] + bb;
  }
}

// ---------------------------------------------------------------------------
// Head (R3-proven): 16 rows/block.
__global__ __launch_bounds__(256, 3)
void head_kernel(const float* __restrict__ g1, const float* __restrict__ g2,
                 const float* __restrict__ cc,
                 const float* __restrict__ Wf1, const float* __restrict__ bf1,
                 const float* __restrict__ Wf2, const float* __restrict__ bf2,
                 const float* __restrict__ Wo, const float* __restrict__ bo,
                 const float* __restrict__ pa, float* __restrict__ out) {
  __shared__ __align__(16) float U[512 * RBK];
  __shared__ __align__(16) float h2[128 * RBK];
  __shared__ float ssq[RBK];
  __shared__ float scal[RBK];
  __shared__ float red[256];

  const int t = threadIdx.x;
  const int R = blockIdx.x * RBK;
  if (t < RBK) ssq[t] = 0.f;
  __syncthreads();
  for (int i = t; i < 1536; i += 256) {
    int r = i / 96, qq = i - r * 96;
    int col = qq * 4;
    const float* src;
    int c2;
    if (col < 128)      { src = g1; c2 = col; }
    else if (col < 256) { src = g2; c2 = col - 128; }
    else                { src = cc; c2 = col - 256; }
    float4 v = *(const float4*)(src + (size_t)(R + r) * GOC + c2);
    U[(col + 0) * RBK + r] = v.x; U[(col + 1) * RBK + r] = v.y;
    U[(col + 2) * RBK + r] = v.z; U[(col + 3) * RBK + r] = v.w;
    atomicAdd(&ssq[r], v.x * v.x + v.y * v.y + v.z * v.z + v.w * v.w);
  }
  __syncthreads();
  if (t < RBK) scal[t] = 1.0f / fmaxf(sqrtf(ssq[t]), 1e-12f);
  __syncthreads();

  const float a = pa[0];
  const int r0 = (t & 3) * 4;
  const int f = t >> 2;

  float acc[4][8];
#pragma unroll
  for (int i = 0; i < 4; ++i)
#pragma unroll
    for (int j = 0; j < 8; ++j) acc[i][j] = 0.f;
#pragma unroll 4
  for (int k = 0; k < 384; ++k) {
    float4 h = *(const float4*)(U + k * RBK + r0);
    const float* wr = Wf1 + (size_t)k * 512 + f;
#pragma unroll
    for (int j = 0; j < 8; ++j) {
      float w = wr[j * 64];
      acc[0][j] = fmaf(h.x, w, acc[0][j]);
      acc[1][j] = fmaf(h.y, w, acc[1][j]);
      acc[2][j] = fmaf(h.z, w, acc[2][j]);
      acc[3][j] = fmaf(h.w, w, acc[3][j]);
    }
  }
  __syncthreads();
#pragma unroll
  for (int j = 0; j < 8; ++j) {
    int ff = f + j * 64;
    float bb = bf1[ff];
    float4 o;
    float v0 = acc[0][j] * scal[r0 + 0] + bb; o.x = v0 >= 0.f ? v0 : a * v0;
    float v1 = acc[1][j] * scal[r0 + 1] + bb; o.y = v1 >= 0.f ? v1 : a * v1;
    float v2 = acc[2][j] * scal[r0 + 2] + bb; o.z = v2 >= 0.f ? v2 : a * v2;
    float v3 = acc[3][j] * scal[r0 + 3] + bb; o.w = v3 >= 0.f ? v3 : a * v3;
    *(float4*)(U + ff * RBK + r0) = o;
  }
  __syncthreads();

  float a2[4][2];
#pragma unroll
  for (int i = 0; i < 4; ++i) { a2[i][0] = 0.f; a2[i][1] = 0.f; }
#pragma unroll 4
  for (int k = 0; k < 512; ++k) {
    float4 h = *(const float4*)(U + k * RBK + r0);
    const float* wr = Wf2 + (size_t)k * 128 + f;
#pragma unroll
    for (int j = 0; j < 2; ++j) {
      float w = wr[j * 64];
      a2[0][j] = fmaf(h.x, w, a2[0][j]);
      a2[1][j] = fmaf(h.y, w, a2[1][j]);
      a2[2][j] = fmaf(h.z, w, a2[2][j]);
      a2[3][j] = fmaf(h.w, w, a2[3][j]);
    }
  }
  {
#pragma unroll
    for (int j = 0; j < 2; ++j) {
      int ff = f + j * 64;
      float bb = bf2[ff];
#pragma unroll
      for (int i = 0; i < 4; ++i) {
        float v = a2[i][j] + bb;
        v = v >= 0.f ? v : a * v;
        h2[ff * RBK + (r0 + i)] = v;
      }
    }
  }
  __syncthreads();

  {
    int rr = t >> 4, kp = t & 15;
    float p = 0.f;
#pragma unroll
    for (int jj = 0; jj < 8; ++jj) {
      int k = kp + 16 * jj;
      p = fmaf(h2[k * RBK + rr], Wo[k], p);
    }
    red[t] = p;
  }
  __syncthreads();
  if (t < RBK) {
    float ssum = bo[0];
#pragma unroll
    for (int i = 0; i < 16; ++i) ssum += red[t * 16 + i];
    out[R + t] = 1.0f / (1.0f + expf(-ssum));
  }
}

// ---------------------------------------------------------------------------
extern "C" void kernel_launch(void* const* d_in, const int* in_sizes, int n_in,
                              void* d_out, int out_size, void* d_ws, size_t ws_size,
                              hipStream_t stream) {
  const float* x1  = (const float*)d_in[0];
  const int*   ei1 = (const int*)d_in[1];
  const float* x2  = (const float*)d_in[2];
  const int*   ei2 = (const int*)d_in[3];
  const float* cel = (const float*)d_in[4];
  const float* W1  = (const float*)d_in[7];
  const float* b1  = (const float*)d_in[8];
  const float* W2  = (const float*)d_in[9];
  const float* b2  = (const float*)d_in[10];
  const float* W3  = (const float*)d_in[11];
  const float* b3  = (const float*)d_in[12];
  const float* Wg1 = (const float*)d_in[13];
  const float* bg1 = (const float*)d_in[14];
  const float* Wg2 = (const float*)d_in[15];
  const float* bg2 = (const float*)d_in[16];
  const float* Wr1 = (const float*)d_in[17];
  const float* br1 = (const float*)d_in[18];
  const float* Wr2 = (const float*)d_in[19];
  const float* br2 = (const float*)d_in[20];
  const float* Wr3 = (const float*)d_in[21];
  const float* br3 = (const float*)d_in[22];
  const float* Wf1 = (const float*)d_in[23];
  const float* bf1 = (const float*)d_in[24];
  const float* Wf2 = (const float*)d_in[25];
  const float* bf2 = (const float*)d_in[26];
  const float* Wo  = (const float*)d_in[27];
  const float* bo  = (const float*)d_in[28];
  const float* pa  = (const float*)d_in[29];

  float* ws    = (float*)d_ws;
  float* g1buf = ws;                                       // [16384 x 128] (g1 then g2)
  float* g2buf = ws + (size_t)N_GRAPHSC * GOC;
  float* cbuf  = ws + (size_t)2 * N_GRAPHSC * GOC;
  float* gpool = ws + (size_t)3 * N_GRAPHSC * GOC;         // [16384 x 312]
  short* wt1   = (short*)(gpool + (size_t)2 * N_GRAPHSC * F3C);  // 80x96
  short* wt2   = wt1 + 80 * 96;                                  // 160x96
  short* wt3   = wt2 + 160 * 96;                                 // 320x160
  float* outp  = (float*)d_out;

  pack_wt<<<dim3((80 * 96 + 255) / 256), dim3(256), 0, stream>>>(W1, wt1, FXD, FXD, 96, 80);
  pack_wt<<<dim3((160 * 96 + 255) / 256), dim3(256), 0, stream>>>(W2, wt2, FXD, F2C, 96, 160);
  pack_wt<<<dim3((320 * 160 + 255) / 256), dim3(256), 0, stream>>>(W3, wt3, F2C, F3C, 160, 320);

  dim3 dgrid(N_GRAPHSC, 2);
  drug_kernel<<<dgrid, dim3(256), 0, stream>>>(
      x1, ei1, x2, ei2, wt1, b1, wt2, b2, wt3, b3, gpool);
  gmlp_kernel<<<dim3(2 * N_GRAPHSC / RBK), dim3(256), 0, stream>>>(
      gpool, Wg1, bg1, Wg2, bg2, g1buf);
  cell_kernel<<<dim3(N_GRAPHSC / RBK), dim3(256), 0, stream>>>(
      cel, Wr1, br1, Wr2, br2, Wr3, br3, cbuf);
  head_kernel<<<dim3(N_GRAPHSC / RBK), dim3(256), 0, stream>>>(
      g1buf, g2buf, cbuf, Wf1, bf1, Wf2, bf2, Wo, bo, pa, outp);
}